// Round 1
// baseline (611.004 us; speedup 1.0000x reference)
//
#include <hip/hip_runtime.h>

// ECC eval forward, fp32 baseline.
// x: (8,512,128,128) f32, prototype: (19,8,512) f32 -> out: (8,19,128,128) f32
//
// Structure: out[b,c,h,w] = 10 * m[n,c], n = b*16384+h*128+w,
//   m_flat[j] = max over 8 consecutive flat elements of d (B,152,H,W),
//   i.e. max over w' in [8g, 8g+8) of d[b',k',h',w'] with
//   j = b'*311296 + k'*2048 + h'*16 + g, then (n,c) = (j/19, j%19).
// So: GEMM (pixels x 152 protos, K=512) -> 8-wide horizontal max -> scatter.

#define NPROTO      152
#define NPROTO_PAD  160
#define CCH         512
#define HW          16384      // 128*128
#define KC          32
#define OUT_SCALE_F 10.0f

// ---------------- kernel 1: normalize prototypes into ws ----------------
// pnW[k][c] for k in [0,160): normalized rows for k<152, zeros otherwise.
__global__ void proto_norm_kernel(const float* __restrict__ proto,
                                  float* __restrict__ pnW) {
    const int k = blockIdx.x;       // 0..159
    const int lane = threadIdx.x;   // 0..63
    if (k < NPROTO) {
        float vals[8];
        float ss = 0.f;
#pragma unroll
        for (int i = 0; i < 8; ++i) {
            vals[i] = proto[k * CCH + lane + i * 64];
            ss += vals[i] * vals[i];
        }
#pragma unroll
        for (int off = 1; off < 64; off <<= 1)
            ss += __shfl_xor(ss, off);
        const float scale = 1.0f / fmaxf(sqrtf(ss), 1e-12f);
#pragma unroll
        for (int i = 0; i < 8; ++i)
            pnW[k * CCH + lane + i * 64] = vals[i] * scale;
    } else {
#pragma unroll
        for (int i = 0; i < 8; ++i)
            pnW[k * CCH + lane + i * 64] = 0.f;
    }
}

// ---------------- kernel 2: fused GEMM + norm + pool + scatter ----------------
__global__ __launch_bounds__(256)
void ecc_main_kernel(const float* __restrict__ x,
                     const float* __restrict__ pnW,
                     float* __restrict__ out) {
    __shared__ float xs[KC][68];          // [kk][pixel], pad 68 for stage-write spread
    __shared__ float ps[NPROTO_PAD][36];  // [proto][kk],  pad 36 -> tq banks 0/8/16/24

    const int tid = threadIdx.x;
    const int tp  = tid & 15;    // pixel group (4 pixels each)
    const int tq  = tid >> 4;    // proto group (10 protos each)

    const int N0  = blockIdx.x * 64;         // global pixel base (64 | N0)
    const int b   = N0 >> 14;                // batch
    const int nb0 = N0 & (HW - 1);           // pixel-in-batch base
    const float* xbase = x + (size_t)b * CCH * HW + nb0;

    float acc[4][10];
    float nrm[4];
#pragma unroll
    for (int i = 0; i < 4; ++i) {
        nrm[i] = 0.f;
#pragma unroll
        for (int j = 0; j < 10; ++j) acc[i][j] = 0.f;
    }

    for (int kc = 0; kc < CCH; kc += KC) {
        // stage x chunk: 32 rows (channels) x 64 pixels
#pragma unroll
        for (int it = 0; it < 2; ++it) {
            const int idx = tid + it * 256;        // 0..511
            const int c  = idx >> 4;               // 0..31
            const int p4 = (idx & 15) * 4;         // 0..60
            const float4 f = *(const float4*)(xbase + (size_t)(kc + c) * HW + p4);
            *(float4*)&xs[c][p4] = f;
        }
        // stage proto chunk: 160 rows x 32 kk
#pragma unroll
        for (int it = 0; it < 5; ++it) {
            const int idx = tid + it * 256;        // 0..1279
            const int r  = idx >> 3;               // 0..159
            const int c4 = (idx & 7) * 4;          // 0..28
            const float4 f = *(const float4*)(pnW + (size_t)r * CCH + kc + c4);
            *(float4*)&ps[r][c4] = f;
        }
        __syncthreads();

#pragma unroll
        for (int kk = 0; kk < KC; kk += 4) {
            float4 pv[10];
#pragma unroll
            for (int j = 0; j < 10; ++j)
                pv[j] = *(const float4*)&ps[tq * 10 + j][kk];
#pragma unroll
            for (int u = 0; u < 4; ++u) {
                const float4 xq = *(const float4*)&xs[kk + u][tp * 4];
                nrm[0] += xq.x * xq.x;
                nrm[1] += xq.y * xq.y;
                nrm[2] += xq.z * xq.z;
                nrm[3] += xq.w * xq.w;
#pragma unroll
                for (int j = 0; j < 10; ++j) {
                    const float pw = (u == 0) ? pv[j].x
                                   : (u == 1) ? pv[j].y
                                   : (u == 2) ? pv[j].z
                                              : pv[j].w;
                    acc[0][j] += xq.x * pw;
                    acc[1][j] += xq.y * pw;
                    acc[2][j] += xq.z * pw;
                    acc[3][j] += xq.w * pw;
                }
            }
        }
        __syncthreads();
    }

    // epilogue: per-pixel 1/||x||, in-thread 4-max, pair 8-max, scatter
    float rn[4];
#pragma unroll
    for (int i = 0; i < 4; ++i)
        rn[i] = 1.0f / fmaxf(sqrtf(nrm[i]), 1e-12f);

    float vmax[10];
#pragma unroll
    for (int j = 0; j < 10; ++j) {
        float v = fmaxf(fmaxf(acc[0][j] * rn[0], acc[1][j] * rn[1]),
                        fmaxf(acc[2][j] * rn[2], acc[3][j] * rn[3]));
        const float o = __shfl_xor(v, 1);   // pair tp even/odd -> 8 pixels
        vmax[j] = fmaxf(v, o);
    }

    if ((tp & 1) == 0) {
        const unsigned gpl = (unsigned)(nb0 >> 3) + (unsigned)(tp >> 1); // group in plane [0,2048)
#pragma unroll
        for (int j = 0; j < 10; ++j) {
            const int k = tq * 10 + j;
            if (k < NPROTO) {
                const unsigned jj  = (unsigned)b * 311296u + (unsigned)k * 2048u + gpl;
                const unsigned cc  = jj % 19u;
                const unsigned nn  = jj / 19u;
                const unsigned bo  = nn >> 14;
                const unsigned rem = nn & 16383u;
                out[((size_t)(bo * 19u + cc) << 14) + rem] = OUT_SCALE_F * vmax[j];
            }
        }
    }
}

extern "C" void kernel_launch(void* const* d_in, const int* in_sizes, int n_in,
                              void* d_out, int out_size, void* d_ws, size_t ws_size,
                              hipStream_t stream) {
    const float* x     = (const float*)d_in[0];   // 8*512*128*128
    const float* proto = (const float*)d_in[1];   // 19*8*512
    float* out = (float*)d_out;                   // 8*19*128*128
    float* pnW = (float*)d_ws;                    // 160*512 floats = 320 KiB scratch

    proto_norm_kernel<<<NPROTO_PAD, 64, 0, stream>>>(proto, pnW);
    ecc_main_kernel<<<131072 / 64, 256, 0, stream>>>(x, pnW, out);
}

// Round 2
// 400.496 us; speedup vs baseline: 1.5256x; 1.5256x over previous
//
#include <hip/hip_runtime.h>

// ECC eval forward, bf16-MFMA version.
// x: (8,512,128,128) f32, prototype: (19,8,512) f32 -> out: (8,19,128,128) f32
//
// out[b,c,h,w] = 10 * m_flat[j] lookup where m_flat[j] = max over 8 consecutive
// flat elements of d (B,152,H,W); j = b*311296 + k*2048 + gpl, (n,c)=(j/19,j%19).
// GEMM (pixels x 152 protos, K=512) on MFMA -> 8-wide pixel max -> scatter.
// Norm of x computed in fp32 from the same staged loads; applied in epilogue.

typedef __attribute__((ext_vector_type(8))) __bf16 bf16x8;
typedef __attribute__((ext_vector_type(4))) float f32x4;
typedef __attribute__((ext_vector_type(8))) unsigned short ushort8;

#define NPROTO 152
#define NPPAD  160
#define CCH    512
#define HW     16384
#define CHUNKS 16          // 512 / 32
#define PSTR   40          // LDS row stride in bf16 elems (80B; quad = 5*row mod 8 -> 2-way, free)
#define PCE    (NPPAD * PSTR)   // proto chunk elems in ws: 6400 (12800 B)
#define OUT_SCALE_F 10.0f

static __device__ __forceinline__ unsigned short f2bf(float f) {
    // round-to-nearest-even f32 -> bf16 (inputs are finite)
    unsigned u = __float_as_uint(f);
    return (unsigned short)((u + 0x7FFFu + ((u >> 16) & 1u)) >> 16);
}

// ---------------- kernel 1: normalize + pack protos (bf16, chunk-major, padded) ----------------
// pnB layout: [chunk 0..15][row 0..159][40], rows >=152 and cols >=32 are zero.
__global__ void proto_pack_kernel(const float* __restrict__ proto,
                                  unsigned short* __restrict__ pnB) {
    const int k = blockIdx.x;       // 0..159
    const int lane = threadIdx.x;   // 0..63
    if (k < NPROTO) {
        float v[8];
        float ss = 0.f;
#pragma unroll
        for (int i = 0; i < 8; ++i) {
            v[i] = proto[k * CCH + lane + i * 64];
            ss += v[i] * v[i];
        }
#pragma unroll
        for (int off = 1; off < 64; off <<= 1)
            ss += __shfl_xor(ss, off);
        const float scale = 1.0f / fmaxf(sqrtf(ss), 1e-12f);
#pragma unroll
        for (int i = 0; i < 8; ++i) {
            const int c = lane + i * 64;                 // channel 0..511
            pnB[(c >> 5) * PCE + k * PSTR + (c & 31)] = f2bf(v[i] * scale);
        }
        // zero the 8 pad cols of this row in all 16 chunks: 128 slots / 64 lanes
#pragma unroll
        for (int jj = 0; jj < 2; ++jj) {
            const int slot = lane + 64 * jj;             // 0..127
            pnB[(slot >> 3) * PCE + k * PSTR + 32 + (slot & 7)] = 0;
        }
    } else {
        // zero whole row in all chunks: 16*40 = 640 slots / 64 lanes
#pragma unroll
        for (int i = 0; i < 10; ++i) {
            const int slot = lane + 64 * i;              // 0..639
            pnB[(slot / PSTR) * PCE + k * PSTR + (slot % PSTR)] = 0;
        }
    }
}

// ---------------- kernel 2: fused MFMA GEMM + norm + pool + scatter ----------------
__global__ __launch_bounds__(256)
void ecc_mfma_kernel(const float* __restrict__ x,
                     const unsigned short* __restrict__ pnB,
                     float* __restrict__ out) {
    __shared__ __align__(16) unsigned short xs[64 * PSTR];     // [pixel][k]   5120 B
    __shared__ __align__(16) unsigned short ps[NPPAD * PSTR];  // [proto][k]  12800 B
    __shared__ float nrm_s[4][64];
    __shared__ float rnorm_s[64];

    const int tid  = threadIdx.x;
    const int lane = tid & 63;
    const int w    = tid >> 6;          // wave id 0..3

    const int N0  = blockIdx.x * 64;    // pixel base
    const int b   = N0 >> 14;
    const int nb0 = N0 & (HW - 1);
    const float* xb = x + (size_t)b * CCH * HW + nb0 + lane;

    f32x4 acc[10];
#pragma unroll
    for (int jt = 0; jt < 10; ++jt) acc[jt] = (f32x4){0.f, 0.f, 0.f, 0.f};
    float ss = 0.f;

    // prefetch chunk 0 globals (thread covers channels w*8..w*8+7 for pixel `lane`)
    float f[8];
#pragma unroll
    for (int i = 0; i < 8; ++i) f[i] = xb[(size_t)(w * 8 + i) * HW];

    for (int ci = 0; ci < CHUNKS; ++ci) {
        // consume prefetched x: norm accum + convert + one b128 LDS write
        ushort8 pk;
#pragma unroll
        for (int i = 0; i < 8; ++i) {
            ss += f[i] * f[i];
            pk[i] = f2bf(f[i]);
        }
        *(ushort8*)&xs[lane * PSTR + w * 8] = pk;

        // stage proto chunk: raw 12800 B copy (800 x 16 B over 256 threads)
        const ushort8* __restrict__ src = (const ushort8*)(pnB + (size_t)ci * PCE);
#pragma unroll
        for (int it = 0; it < 4; ++it) {
            const int idx = it * 256 + tid;
            if (idx < PCE / 8) *(ushort8*)&ps[idx * 8] = src[idx];
        }
        __syncthreads();

        // prefetch next chunk's globals (overlaps the MFMA phase)
        if (ci + 1 < CHUNKS) {
#pragma unroll
            for (int i = 0; i < 8; ++i)
                f[i] = xb[(size_t)((ci + 1) * 32 + w * 8 + i) * HW];
        }

        // fragments + MFMA: wave w owns pixels 16w..16w+15, all 160 protos
        const int l15 = lane & 15, g = lane >> 4;
        const bf16x8 a = *(const bf16x8*)&xs[(16 * w + l15) * PSTR + g * 8];
#pragma unroll
        for (int jt = 0; jt < 10; ++jt) {
            const bf16x8 bq = *(const bf16x8*)&ps[(jt * 16 + l15) * PSTR + g * 8];
            acc[jt] = __builtin_amdgcn_mfma_f32_16x16x32_bf16(a, bq, acc[jt], 0, 0, 0);
        }
        __syncthreads();
    }

    // per-pixel norm: 4 partials (one per wave-channel-group) -> rsqrt
    nrm_s[w][lane] = ss;
    __syncthreads();
    if (tid < 64) {
        const float t = nrm_s[0][tid] + nrm_s[1][tid] + nrm_s[2][tid] + nrm_s[3][tid];
        rnorm_s[tid] = 1.0f / fmaxf(sqrtf(t), 1e-12f);
    }
    __syncthreads();

    // epilogue: scale by rnorm, pool 8 consecutive pixels, scatter
    const int l15 = lane & 15, g = lane >> 4;
    float rn[4];
#pragma unroll
    for (int r = 0; r < 4; ++r) rn[r] = rnorm_s[16 * w + 4 * g + r];

    const unsigned gpl = (unsigned)(nb0 >> 3) + 2u * (unsigned)w + (unsigned)(g >> 1);
    const bool writer = ((g & 1) == 0);
#pragma unroll
    for (int jt = 0; jt < 10; ++jt) {
        float m = fmaxf(fmaxf(acc[jt][0] * rn[0], acc[jt][1] * rn[1]),
                        fmaxf(acc[jt][2] * rn[2], acc[jt][3] * rn[3]));
        m = fmaxf(m, __shfl_xor(m, 16)) * OUT_SCALE_F;
        const int k = jt * 16 + l15;
        if (writer && k < NPROTO) {
            const unsigned j = (unsigned)b * 311296u + (unsigned)k * 2048u + gpl;
            const unsigned n = j / 19u;
            const unsigned c = j % 19u;
            out[(size_t)(n >> 14) * 311296u + (size_t)c * 16384u + (n & 16383u)] = m;
        }
    }
}

extern "C" void kernel_launch(void* const* d_in, const int* in_sizes, int n_in,
                              void* d_out, int out_size, void* d_ws, size_t ws_size,
                              hipStream_t stream) {
    const float* x     = (const float*)d_in[0];   // 8*512*128*128
    const float* proto = (const float*)d_in[1];   // 19*8*512
    float* out = (float*)d_out;                   // 8*19*128*128
    unsigned short* pnB = (unsigned short*)d_ws;  // 16*160*40 bf16 = 200 KiB

    proto_pack_kernel<<<NPPAD, 64, 0, stream>>>(proto, pnB);
    ecc_mfma_kernel<<<131072 / 64, 256, 0, stream>>>(x, pnB, out);
}